// Round 1
// baseline (39331.094 us; speedup 1.0000x reference)
//
#include <hip/hip_runtime.h>
#include <stdint.h>

// AutoRegressiveModel: 47 outer x 512 inner sequential LSTM steps (mid=256),
// Bernoulli sampling bit-matches JAX threefry2x32 (partitionable mode).
//
// Persistent dataflow kernel: 17 blocks x 256 threads.
//   blocks 0..15 : LSTM workers. Block b owns h indices [16b,16b+16).
//   block 16     : init + sampler (p = sigmoid(h.W_out+b), threefry RNG,
//                  logprob/entropy accumulation, obs feedback).
//
// R3 changes vs R2 (31.8 ms):
//  - obs feedback moved OFF the critical path: batched 16-step-ahead
//    prefetch into an LDS ring (flag load -> verify+data load -> ring write
//    pipelined across 3 consecutive steps, once per 16 steps). Removes the
//    per-step acquire + 2 dependent IF$ loads from wave 3's serial chain.
//  - ONE barrier per step (was two): lane remap (lane = gate*16+js*4+p) puts
//    a row's 4 column-partials in adjacent lanes -> 2x shfl_xor reduce +
//    3x shfl gate gather; epilogue runs on all 4 waves in parallel; hstage
//    double-buffered for WAR safety under the single-barrier schedule.
//  - producers write own h slice straight into next hstage (LDS), own-block
//    words skip the global poll.
//  - h-tag spin poll deepened 2 -> 4 outstanding loads.

#define MID      256
#define NOUT     48
#define NSEQ     512
#define NOUTER   47
#define NSTEP    (NOUTER * NSEQ)   // 24064
#define NBLK     16
#define MAGIC_V  0x1234ABCDu
#define LOG2E    1.4426950408889634f

#define LD_REL(p) __hip_atomic_load((p), __ATOMIC_RELAXED, __HIP_MEMORY_SCOPE_AGENT)

__device__ __forceinline__ uint32_t rotl32(uint32_t x, int d) {
  return (x << d) | (x >> (32 - d));
}

// Exact JAX threefry2x32 (20 rounds).
__device__ __forceinline__ void threefry2x32(uint32_t k0, uint32_t k1,
                                             uint32_t x0, uint32_t x1,
                                             uint32_t& o0, uint32_t& o1) {
  uint32_t ks2 = k0 ^ k1 ^ 0x1BD11BDAu;
  uint32_t v0 = x0 + k0, v1 = x1 + k1;
#define TF_R(r) { v0 += v1; v1 = rotl32(v1, r); v1 ^= v0; }
  TF_R(13) TF_R(15) TF_R(26) TF_R(6)
  v0 += k1;  v1 += ks2 + 1u;
  TF_R(17) TF_R(29) TF_R(16) TF_R(24)
  v0 += ks2; v1 += k0 + 2u;
  TF_R(13) TF_R(15) TF_R(26) TF_R(6)
  v0 += k0;  v1 += k1 + 3u;
  TF_R(17) TF_R(29) TF_R(16) TF_R(24)
  v0 += k1;  v1 += ks2 + 4u;
  TF_R(13) TF_R(15) TF_R(26) TF_R(6)
  v0 += ks2; v1 += k0 + 5u;
#undef TF_R
  o0 = v0; o1 = v1;
}

// Accurate sigmoid for the sampler (off critical path).
__device__ __forceinline__ float sigf(float x) { return 1.0f / (1.0f + expf(-x)); }

__device__ __forceinline__ uint64_t packht(float h, uint32_t tag) {
  return ((uint64_t)tag << 32) | (uint64_t)__float_as_uint(h);
}

__global__ __launch_bounds__(256, 1)
void arlstm_kernel(const float* __restrict__ W_ih, const float* __restrict__ W_hh,
                   const float* __restrict__ b_ih, const float* __restrict__ b_hh,
                   const float* __restrict__ W_out, const float* __restrict__ b_out,
                   float* __restrict__ out, uint64_t* __restrict__ ws) {
  // ws layout (u64 units):
  uint64_t* h_hist = ws;                                  // [512][256] tagged
  float*    obsbuf = (float*)(ws + 512 * 256);            // [2][512][2]
  uint32_t* p_prog = (uint32_t*)(obsbuf + 2 * 512 * 2);   // [4] sampler progress
  uint32_t* magic  = p_prog + 16;
  uint64_t* ob64   = (uint64_t*)obsbuf;                   // pair view (8B aligned)

  const int tid = threadIdx.x;
  const int blk = blockIdx.x;

  __shared__ __align__(16) float hstage[2][256];
  __shared__ __align__(16) float ring[2][16][2];
  __shared__ float lp_acc[512];
  __shared__ float ent_acc[512];
  __shared__ float red[256];

  if (blk == NBLK) {
    // ----------------------- init + sampler block -----------------------
    // h_hist slot 0 holds h_0 = 0 with tag 0.
    __hip_atomic_store(&h_hist[tid], 0ull, __ATOMIC_RELAXED, __HIP_MEMORY_SCOPE_AGENT);
    if (tid < 16)
      __hip_atomic_store(&p_prog[tid], 0u, __ATOMIC_RELAXED, __HIP_MEMORY_SCOPE_AGENT);
    out[(tid)       * NOUT] = 0.0f;   // samples column 0 = zeros
    out[(tid + 256) * NOUT] = 0.0f;
    lp_acc[tid] = 0.0f;  lp_acc[tid + 256] = 0.0f;
    ent_acc[tid] = 0.0f; ent_acc[tid + 256] = 0.0f;
    __threadfence();
    __syncthreads();
    if (tid == 0)
      __hip_atomic_store(magic, MAGIC_V, __ATOMIC_RELEASE, __HIP_MEMORY_SCOPE_AGENT);

    const int w    = tid >> 6;   // wave 0..3 handles steps s with (s-1)&3 == w
    const int lane = tid & 63;
    const float wo0 = W_out[lane * 4 + 0], wo1 = W_out[lane * 4 + 1];
    const float wo2 = W_out[lane * 4 + 2], wo3 = W_out[lane * 4 + 3];
    const float bo = b_out[0];

    for (int s = w + 1; s <= NSTEP; s += 4) {
      const int k = (s - 1) >> 9;
      const int t = (s - 1) & 511;
      uint64_t* src = h_hist + (uint64_t)(s & 511) * 256 + lane * 4;
      uint64_t v0, v1, v2, v3;
      for (;;) {
        v0 = LD_REL(src + 0);
        v1 = LD_REL(src + 1);
        v2 = LD_REL(src + 2);
        v3 = LD_REL(src + 3);
        int ok = ((uint32_t)(v0 >> 32) == (uint32_t)s) &
                 ((uint32_t)(v1 >> 32) == (uint32_t)s) &
                 ((uint32_t)(v2 >> 32) == (uint32_t)s) &
                 ((uint32_t)(v3 >> 32) == (uint32_t)s);
        if (__all(ok)) break;
      }
      float zp = fmaf(__uint_as_float((uint32_t)v0), wo0,
                 fmaf(__uint_as_float((uint32_t)v1), wo1,
                 fmaf(__uint_as_float((uint32_t)v2), wo2,
                      __uint_as_float((uint32_t)v3) * wo3)));
      zp += __shfl_xor(zp, 1);
      zp += __shfl_xor(zp, 2);
      zp += __shfl_xor(zp, 4);
      zp += __shfl_xor(zp, 8);
      zp += __shfl_xor(zp, 16);
      zp += __shfl_xor(zp, 32);
      const float p = sigf(zp + bo);

      // JAX partitionable threefry: key_k = tf((0,42),(0,k)); bits = xor of
      // tf(key_k,(0,t)); u = bitcast((bits>>9)|0x3f800000)-1; sample = u < p.
      uint32_t ka, kb, c1, c2;
      threefry2x32(0u, 42u, 0u, (uint32_t)k, ka, kb);
      threefry2x32(ka, kb, 0u, (uint32_t)t, c1, c2);
      const uint32_t bits = c1 ^ c2;
      const float u = __uint_as_float((bits >> 9) | 0x3f800000u) - 1.0f;
      const float smp = (u < p) ? 1.0f : 0.0f;

      if (lane == 0) {
        uint32_t* ob = (uint32_t*)(obsbuf + ((k + 1) & 1) * (512 * 2) + t * 2);
        __hip_atomic_store(&ob[0], __float_as_uint(smp), __ATOMIC_RELAXED, __HIP_MEMORY_SCOPE_AGENT);
        __hip_atomic_store(&ob[1], __float_as_uint(p),   __ATOMIC_RELAXED, __HIP_MEMORY_SCOPE_AGENT);
        __hip_atomic_store(&p_prog[w], (uint32_t)s, __ATOMIC_RELEASE, __HIP_MEMORY_SCOPE_AGENT);
        out[t * NOUT + (k + 1)] = smp;
        const float lg = logf(p), lg1 = log1pf(-p);
        lp_acc[t]  += (smp > 0.5f) ? lg : lg1;
        ent_acc[t] -= (p * lg + (1.0f - p) * lg1);
      }
    }
    __syncthreads();
    // final outputs: logprobs (centered), entropies (mean over 47)
    red[tid] = lp_acc[tid] + lp_acc[tid + 256];
    __syncthreads();
    for (int off = 128; off > 0; off >>= 1) {
      if (tid < off) red[tid] += red[tid + off];
      __syncthreads();
    }
    const float mean = red[0] * (1.0f / 512.0f);
    out[24576 + tid]        = lp_acc[tid]        - mean;
    out[24576 + 256 + tid]  = lp_acc[tid + 256]  - mean;
    out[25088 + tid]        = ent_acc[tid]       * (1.0f / 47.0f);
    out[25088 + 256 + tid]  = ent_acc[tid + 256] * (1.0f / 47.0f);
  } else {
    // --------------------------- LSTM worker ---------------------------
    // lane = gate*16 + js*4 + p ; wave wv handles local j = 4*wv + js.
    const int lane6 = tid & 63;
    const int wv    = tid >> 6;
    const int p     = lane6 & 3;          // column quarter
    const int js    = (lane6 >> 2) & 3;
    const int gate  = lane6 >> 4;
    const int jl    = 4 * wv + js;        // local j 0..15
    const int jglob = blk * 16 + jl;      // global h index
    const int rr    = gate * 256 + blk * 16 + jl;  // row of W (1024x256)

    float wreg[64];
#pragma unroll
    for (int c = 0; c < 64; ++c)
      wreg[c] = W_hh[rr * 256 + p * 64 + c];

    const float bb  = b_ih[rr] + b_hh[rr];
    const float wx0 = W_ih[rr * 2 + 0];
    const float wx1 = W_ih[rr * 2 + 1];
    const float mconst = (gate == 2) ? (-2.0f * LOG2E) : (-LOG2E);  // act = ml*sig(sc*x)+ad
    const float ml     = (gate == 2) ? 2.0f : 1.0f;
    const float ad     = (gate == 2) ? -1.0f : 0.0f;

    if (tid < 16) {  // obs ring: batch 0 (k=0) is all zeros
      ring[0][tid][0] = 0.f; ring[0][tid][1] = 0.f;
      ring[1][tid][0] = 0.f; ring[1][tid][1] = 0.f;
    }

    if (tid == 0) {
      while (__hip_atomic_load(magic, __ATOMIC_ACQUIRE, __HIP_MEMORY_SCOPE_AGENT) != MAGIC_V) {}
    }
    __syncthreads();

    float c_st = 0.0f;                    // cell state (gate-0 lanes)
    const bool own = (tid >= blk * 16) && (tid < blk * 16 + 16);

    // obs prefetch pipeline state (wave 3, lanes 0..15)
    int      pf_tgt = 0, pf_need = 0;
    uint32_t pf_ppv = 0;
    uint64_t pf_ov  = 0;

    for (int s = 1; s <= NSTEP; ++s) {
      const int ph = (s - 1) & 15;

      // ---- obs prefetch machinery: 3-phase, once per 16 steps ----
      if (wv == 3) {
        if (ph == 0) {
          // target steps s+16 .. s+31 (next batch); lane L -> s+16+L
          pf_tgt  = s + 16 + lane6;
          pf_need = 0;
          if (lane6 < 16 && pf_tgt > NSEQ && pf_tgt <= NSTEP) {
            pf_need = pf_tgt - NSEQ;                 // sampler step required
            pf_ppv  = LD_REL(&p_prog[(pf_need - 1) & 3]);
          }
        } else if (ph == 1) {
          bool ok = (pf_need == 0) || (pf_ppv >= (uint32_t)pf_need);
          while (!__all(ok)) {                       // essentially never taken
            if (!ok) pf_ppv = LD_REL(&p_prog[(pf_need - 1) & 3]);
            ok = (pf_need == 0) || (pf_ppv >= (uint32_t)pf_need);
          }
          pf_ov = 0;
          if (lane6 < 16 && pf_need != 0) {          // flag seen -> data safe
            const int kk = (pf_tgt - 1) >> 9;
            const int tt = (pf_tgt - 1) & 511;
            pf_ov = LD_REL(ob64 + (kk & 1) * 512 + tt);
          }
        } else if (ph == 2) {
          if (lane6 < 16) {
            const int par = (((s - 3) >> 4) + 1) & 1;   // parity of batch b+1
            ring[par][lane6][0] = __uint_as_float((uint32_t)pf_ov);
            ring[par][lane6][1] = __uint_as_float((uint32_t)(pf_ov >> 32));
          }
        }
      }

      // ---- 4-deep pipelined spin on own tagged word of h_{s-1} ----
      if (s == 1 || !own) {
        uint64_t* src = h_hist + (uint64_t)((s - 1) & 511) * 256 + tid;
        const uint32_t want = (uint32_t)(s - 1);
        uint64_t v = LD_REL(src);
        if ((uint32_t)(v >> 32) != want) {
          uint64_t q0 = LD_REL(src), q1 = LD_REL(src);
          uint64_t q2 = LD_REL(src), q3 = LD_REL(src);
          for (;;) {
            if ((uint32_t)(q0 >> 32) == want) { v = q0; break; }
            q0 = LD_REL(src);
            if ((uint32_t)(q1 >> 32) == want) { v = q1; break; }
            q1 = LD_REL(src);
            if ((uint32_t)(q2 >> 32) == want) { v = q2; break; }
            q2 = LD_REL(src);
            if ((uint32_t)(q3 >> 32) == want) { v = q3; break; }
            q3 = LD_REL(src);
          }
        }
        hstage[s & 1][tid] = __uint_as_float((uint32_t)v);
      }
      __syncthreads();   // the ONLY barrier per step

      float a0 = 0.f, a1 = 0.f, a2 = 0.f, a3 = 0.f;
      const float4* hs4 = (const float4*)&hstage[s & 1][p * 64];
#pragma unroll
      for (int i = 0; i < 16; ++i) {
        const float4 hv = hs4[i];
        a0 = fmaf(wreg[4 * i + 0], hv.x, a0);
        a1 = fmaf(wreg[4 * i + 1], hv.y, a1);
        a2 = fmaf(wreg[4 * i + 2], hv.z, a2);
        a3 = fmaf(wreg[4 * i + 3], hv.w, a3);
      }
      float gp = (a0 + a1) + (a2 + a3);
      gp += __shfl_xor(gp, 1);   // reduce over column quarters (p)
      gp += __shfl_xor(gp, 2);

      const float sx = ring[((s - 1) >> 4) & 1][ph][0];
      const float px = ring[((s - 1) >> 4) & 1][ph][1];
      const float gv = gp + (wx0 * sx + wx1 * px + bb);

      // act = sig(gv) for gates i,f,o; tanh(gv) = 2*sig(2gv)-1 for gate g.
      const float e   = __builtin_amdgcn_exp2f(gv * mconst);
      const float y   = __builtin_amdgcn_rcpf(1.0f + e);
      const float act = __builtin_fmaf(ml, y, ad);

      const float a_f = __shfl(act, (lane6 & 15) + 16, 64);
      const float a_g = __shfl(act, (lane6 & 15) + 32, 64);
      const float a_o = __shfl(act, (lane6 & 15) + 48, 64);

      if (lane6 < 16) {                       // gate-0 lanes: c/h update
        const float t1 = a_f * c_st;
        const float t2 = act * a_g;           // act = sig(i)
        c_st = t1 + t2;
        const float ec = __builtin_amdgcn_exp2f(c_st * (-2.0f * LOG2E));
        const float yc = __builtin_amdgcn_rcpf(1.0f + ec);
        const float th = __builtin_fmaf(2.0f, yc, -1.0f);
        const float hnew = a_o * th;
        if (p == 0) {                         // one producer per local j
          hstage[(s + 1) & 1][jglob] = hnew;  // own-block short-circuit
          __hip_atomic_store(&h_hist[(uint64_t)(s & 511) * 256 + jglob],
                             packht(hnew, (uint32_t)s),
                             __ATOMIC_RELAXED, __HIP_MEMORY_SCOPE_AGENT);
        }
      }
    }
  }
}

extern "C" void kernel_launch(void* const* d_in, const int* in_sizes, int n_in,
                              void* d_out, int out_size, void* d_ws, size_t ws_size,
                              hipStream_t stream) {
  const float* W_ih  = (const float*)d_in[0];
  const float* W_hh  = (const float*)d_in[1];
  const float* b_ih  = (const float*)d_in[2];
  const float* b_hh  = (const float*)d_in[3];
  const float* W_out = (const float*)d_in[4];
  const float* b_out = (const float*)d_in[5];
  float* out = (float*)d_out;
  uint64_t* ws = (uint64_t*)d_ws;

  arlstm_kernel<<<dim3(NBLK + 1), dim3(256), 0, stream>>>(
      W_ih, W_hh, b_ih, b_hh, W_out, b_out, out, ws);
}

// Round 2
// 37557.562 us; speedup vs baseline: 1.0472x; 1.0472x over previous
//
#include <hip/hip_runtime.h>
#include <stdint.h>

// AutoRegressiveModel: 47 outer x 512 inner sequential LSTM steps (mid=256),
// Bernoulli sampling bit-matches JAX threefry2x32 (partitionable mode).
//
// Persistent dataflow kernel: 17 blocks x 256 threads.
//   blocks 0..15 : LSTM workers. Block b owns h indices [16b,16b+16).
//   block 16     : init + sampler (p = sigmoid(h.W_out+b), threefry RNG,
//                  logprob/entropy accumulation, obs feedback).
//
// R4 changes vs R3 (39.3 ms, regression from bank conflicts + barrier drain):
//  - hstage quarters padded to stride 72 floats (72 mod 32 = 8): the four
//    column-quarter ds_read_b128 streams hit disjoint 4-bank groups ->
//    SQ_LDS_BANK_CONFLICT 2.96e8 -> ~0. (R3's stride 64 aliased all four
//    quarters onto the same banks: 4-way conflict on every read.)
//  - per-step barrier is now raw `s_waitcnt lgkmcnt(0); s_barrier` (LDS-only
//    drain). __syncthreads' implicit vmcnt(0) stalled every wave a full
//    memory round-trip on the spin loads / h-store that were issued right
//    before the barrier. Those now drain in the next spin, off the path.
//  - everything else (lane remap, single barrier, obs prefetch ring, 4-deep
//    spin, own-block LDS short-circuit) kept from R3. FP order identical.

#define MID      256
#define NOUT     48
#define NSEQ     512
#define NOUTER   47
#define NSTEP    (NOUTER * NSEQ)   // 24064
#define NBLK     16
#define MAGIC_V  0x1234ABCDu
#define LOG2E    1.4426950408889634f
#define QSTRIDE  72               // padded quarter stride (floats), 72%32=8

#define LD_REL(p) __hip_atomic_load((p), __ATOMIC_RELAXED, __HIP_MEMORY_SCOPE_AGENT)

// LDS-only barrier: order LDS writes before the barrier, skip vmcnt drain.
#define LDS_BARRIER() do {                                        \
    asm volatile("s_waitcnt lgkmcnt(0)\n\ts_barrier" ::: "memory"); \
    __builtin_amdgcn_sched_barrier(0);                            \
  } while (0)

__device__ __forceinline__ uint32_t rotl32(uint32_t x, int d) {
  return (x << d) | (x >> (32 - d));
}

// Exact JAX threefry2x32 (20 rounds).
__device__ __forceinline__ void threefry2x32(uint32_t k0, uint32_t k1,
                                             uint32_t x0, uint32_t x1,
                                             uint32_t& o0, uint32_t& o1) {
  uint32_t ks2 = k0 ^ k1 ^ 0x1BD11BDAu;
  uint32_t v0 = x0 + k0, v1 = x1 + k1;
#define TF_R(r) { v0 += v1; v1 = rotl32(v1, r); v1 ^= v0; }
  TF_R(13) TF_R(15) TF_R(26) TF_R(6)
  v0 += k1;  v1 += ks2 + 1u;
  TF_R(17) TF_R(29) TF_R(16) TF_R(24)
  v0 += ks2; v1 += k0 + 2u;
  TF_R(13) TF_R(15) TF_R(26) TF_R(6)
  v0 += k0;  v1 += k1 + 3u;
  TF_R(17) TF_R(29) TF_R(16) TF_R(24)
  v0 += k1;  v1 += ks2 + 4u;
  TF_R(13) TF_R(15) TF_R(26) TF_R(6)
  v0 += ks2; v1 += k0 + 5u;
#undef TF_R
  o0 = v0; o1 = v1;
}

// Accurate sigmoid for the sampler (off critical path).
__device__ __forceinline__ float sigf(float x) { return 1.0f / (1.0f + expf(-x)); }

__device__ __forceinline__ uint64_t packht(float h, uint32_t tag) {
  return ((uint64_t)tag << 32) | (uint64_t)__float_as_uint(h);
}

__global__ __launch_bounds__(256, 1)
void arlstm_kernel(const float* __restrict__ W_ih, const float* __restrict__ W_hh,
                   const float* __restrict__ b_ih, const float* __restrict__ b_hh,
                   const float* __restrict__ W_out, const float* __restrict__ b_out,
                   float* __restrict__ out, uint64_t* __restrict__ ws) {
  // ws layout (u64 units):
  uint64_t* h_hist = ws;                                  // [512][256] tagged
  float*    obsbuf = (float*)(ws + 512 * 256);            // [2][512][2]
  uint32_t* p_prog = (uint32_t*)(obsbuf + 2 * 512 * 2);   // [4] sampler progress
  uint32_t* magic  = p_prog + 16;
  uint64_t* ob64   = (uint64_t*)obsbuf;                   // pair view (8B aligned)

  const int tid = threadIdx.x;
  const int blk = blockIdx.x;

  __shared__ __align__(16) float hstage[2][4 * QSTRIDE];  // padded quarters
  __shared__ __align__(16) float ring[2][16][2];
  __shared__ float lp_acc[512];
  __shared__ float ent_acc[512];
  __shared__ float red[256];

  if (blk == NBLK) {
    // ----------------------- init + sampler block -----------------------
    // h_hist slot 0 holds h_0 = 0 with tag 0.
    __hip_atomic_store(&h_hist[tid], 0ull, __ATOMIC_RELAXED, __HIP_MEMORY_SCOPE_AGENT);
    if (tid < 16)
      __hip_atomic_store(&p_prog[tid], 0u, __ATOMIC_RELAXED, __HIP_MEMORY_SCOPE_AGENT);
    out[(tid)       * NOUT] = 0.0f;   // samples column 0 = zeros
    out[(tid + 256) * NOUT] = 0.0f;
    lp_acc[tid] = 0.0f;  lp_acc[tid + 256] = 0.0f;
    ent_acc[tid] = 0.0f; ent_acc[tid + 256] = 0.0f;
    __threadfence();
    __syncthreads();
    if (tid == 0)
      __hip_atomic_store(magic, MAGIC_V, __ATOMIC_RELEASE, __HIP_MEMORY_SCOPE_AGENT);

    const int w    = tid >> 6;   // wave 0..3 handles steps s with (s-1)&3 == w
    const int lane = tid & 63;
    const float wo0 = W_out[lane * 4 + 0], wo1 = W_out[lane * 4 + 1];
    const float wo2 = W_out[lane * 4 + 2], wo3 = W_out[lane * 4 + 3];
    const float bo = b_out[0];

    for (int s = w + 1; s <= NSTEP; s += 4) {
      const int k = (s - 1) >> 9;
      const int t = (s - 1) & 511;
      uint64_t* src = h_hist + (uint64_t)(s & 511) * 256 + lane * 4;
      uint64_t v0, v1, v2, v3;
      for (;;) {
        v0 = LD_REL(src + 0);
        v1 = LD_REL(src + 1);
        v2 = LD_REL(src + 2);
        v3 = LD_REL(src + 3);
        int ok = ((uint32_t)(v0 >> 32) == (uint32_t)s) &
                 ((uint32_t)(v1 >> 32) == (uint32_t)s) &
                 ((uint32_t)(v2 >> 32) == (uint32_t)s) &
                 ((uint32_t)(v3 >> 32) == (uint32_t)s);
        if (__all(ok)) break;
      }
      float zp = fmaf(__uint_as_float((uint32_t)v0), wo0,
                 fmaf(__uint_as_float((uint32_t)v1), wo1,
                 fmaf(__uint_as_float((uint32_t)v2), wo2,
                      __uint_as_float((uint32_t)v3) * wo3)));
      zp += __shfl_xor(zp, 1);
      zp += __shfl_xor(zp, 2);
      zp += __shfl_xor(zp, 4);
      zp += __shfl_xor(zp, 8);
      zp += __shfl_xor(zp, 16);
      zp += __shfl_xor(zp, 32);
      const float p = sigf(zp + bo);

      // JAX partitionable threefry: key_k = tf((0,42),(0,k)); bits = xor of
      // tf(key_k,(0,t)); u = bitcast((bits>>9)|0x3f800000)-1; sample = u < p.
      uint32_t ka, kb, c1, c2;
      threefry2x32(0u, 42u, 0u, (uint32_t)k, ka, kb);
      threefry2x32(ka, kb, 0u, (uint32_t)t, c1, c2);
      const uint32_t bits = c1 ^ c2;
      const float u = __uint_as_float((bits >> 9) | 0x3f800000u) - 1.0f;
      const float smp = (u < p) ? 1.0f : 0.0f;

      if (lane == 0) {
        uint32_t* ob = (uint32_t*)(obsbuf + ((k + 1) & 1) * (512 * 2) + t * 2);
        __hip_atomic_store(&ob[0], __float_as_uint(smp), __ATOMIC_RELAXED, __HIP_MEMORY_SCOPE_AGENT);
        __hip_atomic_store(&ob[1], __float_as_uint(p),   __ATOMIC_RELAXED, __HIP_MEMORY_SCOPE_AGENT);
        __hip_atomic_store(&p_prog[w], (uint32_t)s, __ATOMIC_RELEASE, __HIP_MEMORY_SCOPE_AGENT);
        out[t * NOUT + (k + 1)] = smp;
        const float lg = logf(p), lg1 = log1pf(-p);
        lp_acc[t]  += (smp > 0.5f) ? lg : lg1;
        ent_acc[t] -= (p * lg + (1.0f - p) * lg1);
      }
    }
    __syncthreads();
    // final outputs: logprobs (centered), entropies (mean over 47)
    red[tid] = lp_acc[tid] + lp_acc[tid + 256];
    __syncthreads();
    for (int off = 128; off > 0; off >>= 1) {
      if (tid < off) red[tid] += red[tid + off];
      __syncthreads();
    }
    const float mean = red[0] * (1.0f / 512.0f);
    out[24576 + tid]        = lp_acc[tid]        - mean;
    out[24576 + 256 + tid]  = lp_acc[tid + 256]  - mean;
    out[25088 + tid]        = ent_acc[tid]       * (1.0f / 47.0f);
    out[25088 + 256 + tid]  = ent_acc[tid + 256] * (1.0f / 47.0f);
  } else {
    // --------------------------- LSTM worker ---------------------------
    // lane = gate*16 + js*4 + p ; wave wv handles local j = 4*wv + js.
    const int lane6 = tid & 63;
    const int wv    = tid >> 6;
    const int p     = lane6 & 3;          // column quarter
    const int js    = (lane6 >> 2) & 3;
    const int gate  = lane6 >> 4;
    const int jl    = 4 * wv + js;        // local j 0..15
    const int jglob = blk * 16 + jl;      // global h index
    const int rr    = gate * 256 + blk * 16 + jl;  // row of W (1024x256)

    // padded hstage slots (quarter q element e -> q*QSTRIDE + e%64)
    const int hs_self = (tid >> 6) * QSTRIDE + (tid & 63);
    const int hs_own  = (jglob >> 6) * QSTRIDE + (jglob & 63);

    float wreg[64];
#pragma unroll
    for (int c = 0; c < 64; ++c)
      wreg[c] = W_hh[rr * 256 + p * 64 + c];

    const float bb  = b_ih[rr] + b_hh[rr];
    const float wx0 = W_ih[rr * 2 + 0];
    const float wx1 = W_ih[rr * 2 + 1];
    const float mconst = (gate == 2) ? (-2.0f * LOG2E) : (-LOG2E);  // act = ml*sig(sc*x)+ad
    const float ml     = (gate == 2) ? 2.0f : 1.0f;
    const float ad     = (gate == 2) ? -1.0f : 0.0f;

    if (tid < 16) {  // obs ring: batch 0 (k=0) is all zeros
      ring[0][tid][0] = 0.f; ring[0][tid][1] = 0.f;
      ring[1][tid][0] = 0.f; ring[1][tid][1] = 0.f;
    }

    if (tid == 0) {
      while (__hip_atomic_load(magic, __ATOMIC_ACQUIRE, __HIP_MEMORY_SCOPE_AGENT) != MAGIC_V) {}
    }
    __syncthreads();

    float c_st = 0.0f;                    // cell state (gate-0 lanes)
    const bool own = (tid >= blk * 16) && (tid < blk * 16 + 16);

    // obs prefetch pipeline state (wave 3, lanes 0..15)
    int      pf_tgt = 0, pf_need = 0;
    uint32_t pf_ppv = 0;
    uint64_t pf_ov  = 0;

    for (int s = 1; s <= NSTEP; ++s) {
      const int ph = (s - 1) & 15;

      // ---- obs prefetch machinery: 3-phase, once per 16 steps ----
      if (wv == 3) {
        if (ph == 0) {
          // target steps s+16 .. s+31 (next batch); lane L -> s+16+L
          pf_tgt  = s + 16 + lane6;
          pf_need = 0;
          if (lane6 < 16 && pf_tgt > NSEQ && pf_tgt <= NSTEP) {
            pf_need = pf_tgt - NSEQ;                 // sampler step required
            pf_ppv  = LD_REL(&p_prog[(pf_need - 1) & 3]);
          }
        } else if (ph == 1) {
          bool ok = (pf_need == 0) || (pf_ppv >= (uint32_t)pf_need);
          while (!__all(ok)) {                       // essentially never taken
            if (!ok) pf_ppv = LD_REL(&p_prog[(pf_need - 1) & 3]);
            ok = (pf_need == 0) || (pf_ppv >= (uint32_t)pf_need);
          }
          pf_ov = 0;
          if (lane6 < 16 && pf_need != 0) {          // flag seen -> data safe
            const int kk = (pf_tgt - 1) >> 9;
            const int tt = (pf_tgt - 1) & 511;
            pf_ov = LD_REL(ob64 + (kk & 1) * 512 + tt);
          }
        } else if (ph == 2) {
          if (lane6 < 16) {
            const int par = (((s - 3) >> 4) + 1) & 1;   // parity of batch b+1
            ring[par][lane6][0] = __uint_as_float((uint32_t)pf_ov);
            ring[par][lane6][1] = __uint_as_float((uint32_t)(pf_ov >> 32));
          }
        }
      }

      // ---- 4-deep pipelined spin on own tagged word of h_{s-1} ----
      if (s == 1 || !own) {
        uint64_t* src = h_hist + (uint64_t)((s - 1) & 511) * 256 + tid;
        const uint32_t want = (uint32_t)(s - 1);
        uint64_t v = LD_REL(src);
        if ((uint32_t)(v >> 32) != want) {
          uint64_t q0 = LD_REL(src), q1 = LD_REL(src);
          uint64_t q2 = LD_REL(src), q3 = LD_REL(src);
          for (;;) {
            if ((uint32_t)(q0 >> 32) == want) { v = q0; break; }
            q0 = LD_REL(src);
            if ((uint32_t)(q1 >> 32) == want) { v = q1; break; }
            q1 = LD_REL(src);
            if ((uint32_t)(q2 >> 32) == want) { v = q2; break; }
            q2 = LD_REL(src);
            if ((uint32_t)(q3 >> 32) == want) { v = q3; break; }
            q3 = LD_REL(src);
          }
        }
        hstage[s & 1][hs_self] = __uint_as_float((uint32_t)v);
      }
      LDS_BARRIER();   // lgkmcnt(0)+s_barrier only; vm ops stay in flight

      float a0 = 0.f, a1 = 0.f, a2 = 0.f, a3 = 0.f;
      const float4* hs4 = (const float4*)&hstage[s & 1][p * QSTRIDE];
#pragma unroll
      for (int i = 0; i < 16; ++i) {
        const float4 hv = hs4[i];
        a0 = fmaf(wreg[4 * i + 0], hv.x, a0);
        a1 = fmaf(wreg[4 * i + 1], hv.y, a1);
        a2 = fmaf(wreg[4 * i + 2], hv.z, a2);
        a3 = fmaf(wreg[4 * i + 3], hv.w, a3);
      }
      float gp = (a0 + a1) + (a2 + a3);
      gp += __shfl_xor(gp, 1);   // reduce over column quarters (p)
      gp += __shfl_xor(gp, 2);

      const float sx = ring[((s - 1) >> 4) & 1][ph][0];
      const float px = ring[((s - 1) >> 4) & 1][ph][1];
      const float gv = gp + (wx0 * sx + wx1 * px + bb);

      // act = sig(gv) for gates i,f,o; tanh(gv) = 2*sig(2gv)-1 for gate g.
      const float e   = __builtin_amdgcn_exp2f(gv * mconst);
      const float y   = __builtin_amdgcn_rcpf(1.0f + e);
      const float act = __builtin_fmaf(ml, y, ad);

      const float a_f = __shfl(act, (lane6 & 15) + 16, 64);
      const float a_g = __shfl(act, (lane6 & 15) + 32, 64);
      const float a_o = __shfl(act, (lane6 & 15) + 48, 64);

      if (lane6 < 16) {                       // gate-0 lanes: c/h update
        const float t1 = a_f * c_st;
        const float t2 = act * a_g;           // act = sig(i)
        c_st = t1 + t2;
        const float ec = __builtin_amdgcn_exp2f(c_st * (-2.0f * LOG2E));
        const float yc = __builtin_amdgcn_rcpf(1.0f + ec);
        const float th = __builtin_fmaf(2.0f, yc, -1.0f);
        const float hnew = a_o * th;
        if (p == 0) {                         // one producer per local j
          hstage[(s + 1) & 1][hs_own] = hnew; // own-block short-circuit
          __hip_atomic_store(&h_hist[(uint64_t)(s & 511) * 256 + jglob],
                             packht(hnew, (uint32_t)s),
                             __ATOMIC_RELAXED, __HIP_MEMORY_SCOPE_AGENT);
        }
      }
    }
  }
}

extern "C" void kernel_launch(void* const* d_in, const int* in_sizes, int n_in,
                              void* d_out, int out_size, void* d_ws, size_t ws_size,
                              hipStream_t stream) {
  const float* W_ih  = (const float*)d_in[0];
  const float* W_hh  = (const float*)d_in[1];
  const float* b_ih  = (const float*)d_in[2];
  const float* b_hh  = (const float*)d_in[3];
  const float* W_out = (const float*)d_in[4];
  const float* b_out = (const float*)d_in[5];
  float* out = (float*)d_out;
  uint64_t* ws = (uint64_t*)d_ws;

  arlstm_kernel<<<dim3(NBLK + 1), dim3(256), 0, stream>>>(
      W_ih, W_hh, b_ih, b_hh, W_out, b_out, out, ws);
}

// Round 3
// 32565.668 us; speedup vs baseline: 1.2077x; 1.1533x over previous
//
#include <hip/hip_runtime.h>
#include <stdint.h>

// AutoRegressiveModel: 47 outer x 512 inner sequential LSTM steps (mid=256),
// Bernoulli sampling bit-matches JAX threefry2x32 (partitionable mode).
//
// Persistent dataflow kernel: 17 blocks x 256 threads.
//   blocks 0..15 : LSTM workers. Block b owns h indices [16b,16b+16).
//   block 16     : init + sampler (p = sigmoid(h.W_out+b), threefry RNG,
//                  logprob/entropy accumulation, obs feedback).
//
// R5 = R2 structure (31.8 ms best; broadcast matvec, two barriers, one-wave
// epilogue) + four surgical changes (R3/R4's lane remap carried an
// unexplained ~580cy/step cost and is reverted):
//  - both per-step barriers are LDS-only (s_waitcnt lgkmcnt(0); s_barrier):
//    no vmcnt(0) drain on in-flight spin loads / h-store.   [~-500cy]
//  - wave3's serial obs chain (acquire p_prog ~600cy -> obs load ~600cy,
//    before its spin, straggling barrier1 every step) replaced by the R4
//    obs-ring prefetch: 3-phase, once per 16 steps, 490-step slack,
//    flag-checked before data issue.                         [~-800cy]
//  - own-block h short-circuit via LDS (producers write hstage directly;
//    own threads skip the global round-trip). WAR-safe: producer writes
//    after barrier2, all step-s reads drained at barrier2.
//  - W_hh pinned in VGPRs via empty asm "+v": VGPR_Count=56 proved wreg[64]
//    was rematerialized as 16 global loads per step inside the matvec.
//  - spin poll deepened to 4 outstanding loads.

#define MID      256
#define NOUT     48
#define NSEQ     512
#define NOUTER   47
#define NSTEP    (NOUTER * NSEQ)   // 24064
#define NBLK     16
#define MAGIC_V  0x1234ABCDu
#define LOG2E    1.4426950408889634f

typedef __attribute__((ext_vector_type(4))) float f32x4;

#define LD_REL(p) __hip_atomic_load((p), __ATOMIC_RELAXED, __HIP_MEMORY_SCOPE_AGENT)

// LDS-only barrier: order LDS ops before the barrier, skip vmcnt drain.
#define LDS_BARRIER() do {                                          \
    asm volatile("s_waitcnt lgkmcnt(0)\n\ts_barrier" ::: "memory"); \
    __builtin_amdgcn_sched_barrier(0);                              \
  } while (0)

__device__ __forceinline__ uint32_t rotl32(uint32_t x, int d) {
  return (x << d) | (x >> (32 - d));
}

// Exact JAX threefry2x32 (20 rounds).
__device__ __forceinline__ void threefry2x32(uint32_t k0, uint32_t k1,
                                             uint32_t x0, uint32_t x1,
                                             uint32_t& o0, uint32_t& o1) {
  uint32_t ks2 = k0 ^ k1 ^ 0x1BD11BDAu;
  uint32_t v0 = x0 + k0, v1 = x1 + k1;
#define TF_R(r) { v0 += v1; v1 = rotl32(v1, r); v1 ^= v0; }
  TF_R(13) TF_R(15) TF_R(26) TF_R(6)
  v0 += k1;  v1 += ks2 + 1u;
  TF_R(17) TF_R(29) TF_R(16) TF_R(24)
  v0 += ks2; v1 += k0 + 2u;
  TF_R(13) TF_R(15) TF_R(26) TF_R(6)
  v0 += k0;  v1 += k1 + 3u;
  TF_R(17) TF_R(29) TF_R(16) TF_R(24)
  v0 += k1;  v1 += ks2 + 4u;
  TF_R(13) TF_R(15) TF_R(26) TF_R(6)
  v0 += ks2; v1 += k0 + 5u;
#undef TF_R
  o0 = v0; o1 = v1;
}

// Accurate sigmoid for the sampler (off critical path).
__device__ __forceinline__ float sigf(float x) { return 1.0f / (1.0f + expf(-x)); }

__device__ __forceinline__ uint64_t packht(float h, uint32_t tag) {
  return ((uint64_t)tag << 32) | (uint64_t)__float_as_uint(h);
}

__global__ __launch_bounds__(256, 1)
void arlstm_kernel(const float* __restrict__ W_ih, const float* __restrict__ W_hh,
                   const float* __restrict__ b_ih, const float* __restrict__ b_hh,
                   const float* __restrict__ W_out, const float* __restrict__ b_out,
                   float* __restrict__ out, uint64_t* __restrict__ ws) {
  // ws layout (u64 units):
  uint64_t* h_hist = ws;                                  // [512][256] tagged
  float*    obsbuf = (float*)(ws + 512 * 256);            // [2][512][2]
  uint32_t* p_prog = (uint32_t*)(obsbuf + 2 * 512 * 2);   // [4] sampler progress
  uint32_t* magic  = p_prog + 16;
  uint64_t* ob64   = (uint64_t*)obsbuf;                   // pair view (8B aligned)

  const int tid = threadIdx.x;
  const int blk = blockIdx.x;

  __shared__ __align__(16) float hstage[256];
  __shared__ float plds[4][64];
  __shared__ float ring[2][16][2];
  __shared__ float lp_acc[512];
  __shared__ float ent_acc[512];
  __shared__ float red[256];

  if (blk == NBLK) {
    // ----------------------- init + sampler block -----------------------
    // h_hist slot 0 holds h_0 = 0 with tag 0.
    __hip_atomic_store(&h_hist[tid], 0ull, __ATOMIC_RELAXED, __HIP_MEMORY_SCOPE_AGENT);
    if (tid < 16)
      __hip_atomic_store(&p_prog[tid], 0u, __ATOMIC_RELAXED, __HIP_MEMORY_SCOPE_AGENT);
    out[(tid)       * NOUT] = 0.0f;   // samples column 0 = zeros
    out[(tid + 256) * NOUT] = 0.0f;
    lp_acc[tid] = 0.0f;  lp_acc[tid + 256] = 0.0f;
    ent_acc[tid] = 0.0f; ent_acc[tid + 256] = 0.0f;
    __threadfence();
    __syncthreads();
    if (tid == 0)
      __hip_atomic_store(magic, MAGIC_V, __ATOMIC_RELEASE, __HIP_MEMORY_SCOPE_AGENT);

    const int w    = tid >> 6;   // wave 0..3 handles steps s with (s-1)&3 == w
    const int lane = tid & 63;
    const float wo0 = W_out[lane * 4 + 0], wo1 = W_out[lane * 4 + 1];
    const float wo2 = W_out[lane * 4 + 2], wo3 = W_out[lane * 4 + 3];
    const float bo = b_out[0];

    for (int s = w + 1; s <= NSTEP; s += 4) {
      const int k = (s - 1) >> 9;
      const int t = (s - 1) & 511;
      uint64_t* src = h_hist + (uint64_t)(s & 511) * 256 + lane * 4;
      uint64_t v0, v1, v2, v3;
      for (;;) {
        v0 = LD_REL(src + 0);
        v1 = LD_REL(src + 1);
        v2 = LD_REL(src + 2);
        v3 = LD_REL(src + 3);
        int ok = ((uint32_t)(v0 >> 32) == (uint32_t)s) &
                 ((uint32_t)(v1 >> 32) == (uint32_t)s) &
                 ((uint32_t)(v2 >> 32) == (uint32_t)s) &
                 ((uint32_t)(v3 >> 32) == (uint32_t)s);
        if (__all(ok)) break;
      }
      float zp = fmaf(__uint_as_float((uint32_t)v0), wo0,
                 fmaf(__uint_as_float((uint32_t)v1), wo1,
                 fmaf(__uint_as_float((uint32_t)v2), wo2,
                      __uint_as_float((uint32_t)v3) * wo3)));
      zp += __shfl_xor(zp, 1);
      zp += __shfl_xor(zp, 2);
      zp += __shfl_xor(zp, 4);
      zp += __shfl_xor(zp, 8);
      zp += __shfl_xor(zp, 16);
      zp += __shfl_xor(zp, 32);
      const float p = sigf(zp + bo);

      // JAX partitionable threefry: key_k = tf((0,42),(0,k)); bits = xor of
      // tf(key_k,(0,t)); u = bitcast((bits>>9)|0x3f800000)-1; sample = u < p.
      uint32_t ka, kb, c1, c2;
      threefry2x32(0u, 42u, 0u, (uint32_t)k, ka, kb);
      threefry2x32(ka, kb, 0u, (uint32_t)t, c1, c2);
      const uint32_t bits = c1 ^ c2;
      const float u = __uint_as_float((bits >> 9) | 0x3f800000u) - 1.0f;
      const float smp = (u < p) ? 1.0f : 0.0f;

      if (lane == 0) {
        uint32_t* ob = (uint32_t*)(obsbuf + ((k + 1) & 1) * (512 * 2) + t * 2);
        __hip_atomic_store(&ob[0], __float_as_uint(smp), __ATOMIC_RELAXED, __HIP_MEMORY_SCOPE_AGENT);
        __hip_atomic_store(&ob[1], __float_as_uint(p),   __ATOMIC_RELAXED, __HIP_MEMORY_SCOPE_AGENT);
        __hip_atomic_store(&p_prog[w], (uint32_t)s, __ATOMIC_RELEASE, __HIP_MEMORY_SCOPE_AGENT);
        out[t * NOUT + (k + 1)] = smp;
        const float lg = logf(p), lg1 = log1pf(-p);
        lp_acc[t]  += (smp > 0.5f) ? lg : lg1;
        ent_acc[t] -= (p * lg + (1.0f - p) * lg1);
      }
    }
    __syncthreads();
    // final outputs: logprobs (centered), entropies (mean over 47)
    red[tid] = lp_acc[tid] + lp_acc[tid + 256];
    __syncthreads();
    for (int off = 128; off > 0; off >>= 1) {
      if (tid < off) red[tid] += red[tid + off];
      __syncthreads();
    }
    const float mean = red[0] * (1.0f / 512.0f);
    out[24576 + tid]        = lp_acc[tid]        - mean;
    out[24576 + 256 + tid]  = lp_acc[tid + 256]  - mean;
    out[25088 + tid]        = ent_acc[tid]       * (1.0f / 47.0f);
    out[25088 + 256 + tid]  = ent_acc[tid + 256] * (1.0f / 47.0f);
  } else {
    // --------------------------- LSTM worker ---------------------------
    const int part = tid >> 6;          // wave id = column quarter 0..3
    const int r    = tid & 63;          // local row (gate*16 + jloc)
    const int gate = r >> 4;
    const int jloc = r & 15;
    const int row  = gate * 256 + blk * 16 + jloc;

    // W_hh slice in true VGPRs (asm pin prevents rematerialized reloads).
    f32x4 w4[16];
    const f32x4* wsrc = (const f32x4*)(W_hh + row * 256 + part * 64);
#pragma unroll
    for (int i = 0; i < 16; ++i) w4[i] = wsrc[i];
#pragma unroll
    for (int i = 0; i < 16; ++i) asm volatile("" : "+v"(w4[i]));

    // Per-lane epilogue constants (lanes 0..63: lane = gate*16 + j).
    float bb = 0.f, wx0 = 0.f, wx1 = 0.f, mconst = 0.f, ml = 0.f, ad = 0.f;
    if (tid < 64) {
      const int g4 = tid >> 4;
      const int rr = g4 * 256 + blk * 16 + (tid & 15);
      bb  = b_ih[rr] + b_hh[rr];
      wx0 = W_ih[rr * 2 + 0];
      wx1 = W_ih[rr * 2 + 1];
      mconst = (g4 == 2) ? (-2.0f * LOG2E) : (-LOG2E);  // act = ml*sig(sc*x)+ad
      ml     = (g4 == 2) ? 2.0f : 1.0f;
      ad     = (g4 == 2) ? -1.0f : 0.0f;
    }

    if (tid < 16) {  // obs ring: batch 0 (k=0) is all zeros
      ring[0][tid][0] = 0.f; ring[0][tid][1] = 0.f;
      ring[1][tid][0] = 0.f; ring[1][tid][1] = 0.f;
    }

    if (tid == 0) {
      while (__hip_atomic_load(magic, __ATOMIC_ACQUIRE, __HIP_MEMORY_SCOPE_AGENT) != MAGIC_V) {}
    }
    __syncthreads();

    float c_st = 0.0f;                      // cell state (lanes 0..15)
    const int jglob = blk * 16 + (tid & 15);
    const bool own = (tid >= blk * 16) && (tid < blk * 16 + 16);

    // obs prefetch pipeline state (wave 3, lanes 0..15)
    int      pf_tgt = 0, pf_need = 0;
    uint32_t pf_ppv = 0;
    uint64_t pf_ov  = 0;

    for (int s = 1; s <= NSTEP; ++s) {
      const int ph = (s - 1) & 15;

      // ---- obs prefetch machinery: 3-phase, once per 16 steps (wave 3) ----
      if (part == 3) {
        if (ph == 0) {
          // target steps s+16 .. s+31 (next batch); lane L -> s+16+L
          pf_tgt  = s + 16 + r;
          pf_need = 0;
          if (r < 16 && pf_tgt > NSEQ && pf_tgt <= NSTEP) {
            pf_need = pf_tgt - NSEQ;                 // sampler step required
            pf_ppv  = LD_REL(&p_prog[(pf_need - 1) & 3]);
          }
        } else if (ph == 1) {
          bool ok = (pf_need == 0) || (pf_ppv >= (uint32_t)pf_need);
          while (!__all(ok)) {                       // essentially never taken
            if (!ok) pf_ppv = LD_REL(&p_prog[(pf_need - 1) & 3]);
            ok = (pf_need == 0) || (pf_ppv >= (uint32_t)pf_need);
          }
          pf_ov = 0;
          if (r < 16 && pf_need != 0) {              // flag seen -> data safe
            const int kk = (pf_tgt - 1) >> 9;
            const int tt = (pf_tgt - 1) & 511;
            pf_ov = LD_REL(ob64 + (kk & 1) * 512 + tt);
          }
        } else if (ph == 2) {
          if (r < 16) {
            const int par = (((s - 3) >> 4) + 1) & 1;   // parity of batch b+1
            ring[par][r][0] = __uint_as_float((uint32_t)pf_ov);
            ring[par][r][1] = __uint_as_float((uint32_t)(pf_ov >> 32));
          }
        }
      }

      // ---- 4-deep pipelined spin on own tagged word of h_{s-1} ----
      // own-block words arrive via LDS short-circuit (producer wrote hstage).
      if (s == 1 || !own) {
        uint64_t* src = h_hist + (uint64_t)((s - 1) & 511) * 256 + tid;
        const uint32_t want = (uint32_t)(s - 1);
        uint64_t v = LD_REL(src);
        if ((uint32_t)(v >> 32) != want) {
          uint64_t q0 = LD_REL(src), q1 = LD_REL(src);
          uint64_t q2 = LD_REL(src), q3 = LD_REL(src);
          for (;;) {
            if ((uint32_t)(q0 >> 32) == want) { v = q0; break; }
            q0 = LD_REL(src);
            if ((uint32_t)(q1 >> 32) == want) { v = q1; break; }
            q1 = LD_REL(src);
            if ((uint32_t)(q2 >> 32) == want) { v = q2; break; }
            q2 = LD_REL(src);
            if ((uint32_t)(q3 >> 32) == want) { v = q3; break; }
            q3 = LD_REL(src);
          }
        }
        hstage[tid] = __uint_as_float((uint32_t)v);
      }
      LDS_BARRIER();   // barrier 1: hstage ready (LDS only, no vmcnt drain)

      float a0 = 0.f, a1 = 0.f, a2 = 0.f, a3 = 0.f;
      const f32x4* hs4 = (const f32x4*)(hstage + part * 64);
#pragma unroll
      for (int i = 0; i < 16; ++i) {
        const f32x4 hv = hs4[i];           // same-address broadcast read
        a0 = fmaf(w4[i][0], hv[0], a0);
        a1 = fmaf(w4[i][1], hv[1], a1);
        a2 = fmaf(w4[i][2], hv[2], a2);
        a3 = fmaf(w4[i][3], hv[3], a3);
      }
      plds[part][r] = (a0 + a1) + (a2 + a3);
      LDS_BARRIER();   // barrier 2: plds ready (LDS only)

      if (tid < 64) {
        // One gate per lane: gv = full gate pre-activation.
        const float sx = ring[((s - 1) >> 4) & 1][ph][0];
        const float px = ring[((s - 1) >> 4) & 1][ph][1];
        const float base = wx0 * sx + wx1 * px + bb;
        const float gv = ((plds[0][tid] + plds[1][tid]) +
                          (plds[2][tid] + plds[3][tid])) + base;
        // act = sig(gv) for gates i,f,o; tanh(gv) = 2*sig(2gv)-1 for gate g.
        const float e   = __builtin_amdgcn_exp2f(gv * mconst);
        const float y   = __builtin_amdgcn_rcpf(1.0f + e);
        const float act = __builtin_fmaf(ml, y, ad);
        const int j = tid & 15;
        const float a_f = __shfl(act, j + 16, 64);
        const float a_g = __shfl(act, j + 32, 64);
        const float a_o = __shfl(act, j + 48, 64);
        if (tid < 16) {
          const float t1 = a_f * c_st;
          const float t2 = act * a_g;     // act = sig(i) on lanes 0..15
          c_st = t1 + t2;
          const float ec = __builtin_amdgcn_exp2f(c_st * (-2.0f * LOG2E));
          const float yc = __builtin_amdgcn_rcpf(1.0f + ec);
          const float th = __builtin_fmaf(2.0f, yc, -1.0f);
          const float hnew = a_o * th;
          hstage[jglob] = hnew;           // own-block short-circuit (WAR-safe:
                                          // all step-s reads drained at barrier2)
          __hip_atomic_store(&h_hist[(uint64_t)(s & 511) * 256 + jglob],
                             packht(hnew, (uint32_t)s),
                             __ATOMIC_RELAXED, __HIP_MEMORY_SCOPE_AGENT);
        }
      }
    }
  }
}

extern "C" void kernel_launch(void* const* d_in, const int* in_sizes, int n_in,
                              void* d_out, int out_size, void* d_ws, size_t ws_size,
                              hipStream_t stream) {
  const float* W_ih  = (const float*)d_in[0];
  const float* W_hh  = (const float*)d_in[1];
  const float* b_ih  = (const float*)d_in[2];
  const float* b_hh  = (const float*)d_in[3];
  const float* W_out = (const float*)d_in[4];
  const float* b_out = (const float*)d_in[5];
  float* out = (float*)d_out;
  uint64_t* ws = (uint64_t*)d_ws;

  arlstm_kernel<<<dim3(NBLK + 1), dim3(256), 0, stream>>>(
      W_ih, W_hh, b_ih, b_hh, W_out, b_out, out, ws);
}